// Round 13
// baseline (220.906 us; speedup 1.0000x reference)
//
#include <hip/hip_runtime.h>

typedef __bf16 bf16;
typedef __bf16 bf16x4 __attribute__((ext_vector_type(4)));
typedef __bf16 bf16x8 __attribute__((ext_vector_type(8)));
typedef float  f32x4  __attribute__((ext_vector_type(4)));
typedef float  f32x16 __attribute__((ext_vector_type(16)));
typedef unsigned int u32x4v __attribute__((ext_vector_type(4)));

#define NB   4
#define SEQ  2048
#define DM   1024
#define NH   16
#define HD   64
#define BHN  (NB*NH)       // 64
#define MTOT (NB*SEQ)      // 8192
#define ELEMS ((size_t)MTOT*DM)  // 8388608
#define WELEMS (DM*DM)     // 1048576
#define QSCALE 0.18033688011112042f   // 0.125 * log2(e): scores in log2 units

__device__ __forceinline__ void gload16(void* lds, const void* g) {
  __builtin_amdgcn_global_load_lds(
      (const __attribute__((address_space(1))) void*)g,
      (__attribute__((address_space(3))) void*)lds, 16, 0, 0);
}

__device__ __forceinline__ f32x4 mfma16(bf16x8 a, bf16x8 b, f32x4 c) {
  return __builtin_amdgcn_mfma_f32_16x16x32_bf16(a, b, c, 0, 0, 0);
}
__device__ __forceinline__ f32x16 mfma32(bf16x8 a, bf16x8 b, f32x16 c) {
  return __builtin_amdgcn_mfma_f32_32x32x16_bf16(a, b, c, 0, 0, 0);
}
__device__ __forceinline__ unsigned cvtpk(float lo, float hi) {
  unsigned r;
  asm("v_cvt_pk_bf16_f32 %0, %1, %2" : "=v"(r) : "v"(lo), "v"(hi));
  return r;
}
__device__ __forceinline__ float exp2a(float x) {   // D = 2^x
  float r;
  asm("v_exp_f32 %0, %1" : "=v"(r) : "v"(x));
  return r;
}

// fp32 -> bf16 conversion: y=0..3 -> W_y, y=4 -> x
__global__ __launch_bounds__(256) void cvt_all(
    const float* __restrict__ x, bf16* __restrict__ xb,
    const float* __restrict__ w0, const float* __restrict__ w1,
    const float* __restrict__ w2, const float* __restrict__ w3,
    bf16* __restrict__ wb)
{
  int y = blockIdx.y;
  const float* src; bf16* dst; int nblk;
  if (y < 4) {
    src = (y == 0) ? w0 : (y == 1) ? w1 : (y == 2) ? w2 : w3;
    dst = wb + (size_t)y * WELEMS;
    nblk = WELEMS / 1024;
  } else {
    src = x; dst = xb; nblk = (int)(ELEMS / 1024);
  }
  if (blockIdx.x >= nblk) return;
  int i = blockIdx.x * 1024 + threadIdx.x * 4;
  f32x4 v = *(const f32x4*)(src + i);
  bf16x4 o;
#pragma unroll
  for (int j = 0; j < 4; j++) o[j] = (bf16)v[j];
  *(bf16x4*)(dst + i) = o;
}

// ============ 256x128 4-phase counted-vmcnt GEMM skeleton (proven r12) ======
// Per K-tile: P0..P3 quadrant MFMA, staging units {B, Ah0, Ah1} issued JIT,
// vmcnt(2) at TOP / vmcnt(4) at MID, XOR-swizzled LDS, setprio on MFMA.

// Fused QKV: C[8192,3072] = x @ [Wq|Wk|Wv]^T + bias -> Q/K [B,H,S,hd], Vt [B,H,hd,S]
__global__ __launch_bounds__(512, 2) void gemm_qkv256(
    const bf16* __restrict__ A, const bf16* __restrict__ Wb3,
    const float* __restrict__ bq, const float* __restrict__ bk,
    const float* __restrict__ bv,
    bf16* __restrict__ Qb, bf16* __restrict__ Kb, bf16* __restrict__ Vtb)
{
  __shared__ __align__(16) bf16 la[2][256*64];   // A tile [row][k], swz u^=(row&7)
  __shared__ __align__(16) bf16 lb[2][128*64];   // W tile [row][k], same swz

  const int K = 1024;
  int tid = threadIdx.x, wid = tid >> 6, lane = tid & 63;
  int wr = wid >> 1, wc = wid & 1;               // 4M x 2N wave grid
  int c15 = lane & 15, hi = lane >> 4, l7 = lane & 7;

  // XCD map: XCD owns 4 contiguous by (2MB A, L2-resident); by fastest.
  int orig = blockIdx.x;
  int xcd = orig & 7, j = orig >> 3;             // j in 0..95
  int by = xcd * 4 + (j & 3);
  int bx = j >> 2;
  int m0 = by * 256, n0 = bx * 128;
  int z  = n0 >> 10;                             // 0=Q 1=K 2=V
  const float* bias = (z == 0) ? bq : (z == 1) ? bk : bv;

  int r8 = lane >> 3;
  int cu = (lane & 7) ^ r8;

  const bf16* gA = A   + (size_t)m0 * K;
  const bf16* gW = Wb3 + (size_t)n0 * K;

#define STA(buf, h, kt)                                                        \
  {                                                                            \
    _Pragma("unroll")                                                          \
    for (int op = 0; op < 2; op++) {                                           \
      int rowl = (h)*128 + wid*16 + op*8 + r8;                                 \
      gload16(&la[buf][((h)*128 + wid*16 + op*8)*64],                          \
              gA + (size_t)rowl*K + (kt)*64 + cu*8);                           \
    }                                                                          \
  }
#define STB(buf, kt)                                                           \
  {                                                                            \
    _Pragma("unroll")                                                          \
    for (int op = 0; op < 2; op++) {                                           \
      int rowl = wid*16 + op*8 + r8;                                           \
      gload16(&lb[buf][(wid*16 + op*8)*64],                                    \
              gW + (size_t)rowl*K + (kt)*64 + cu*8);                           \
    }                                                                          \
  }

  f32x4 acc[4][4] = {};
  const int NT = K / 64;                         // 16

  STB(0, 0);
  STA(0, 0, 0);
  STA(0, 1, 0);

  for (int t = 0; t < NT; ++t) {
    int cb = t & 1, nb = cb ^ 1;
    asm volatile("s_waitcnt vmcnt(2)" ::: "memory");
    __builtin_amdgcn_s_barrier();
    asm volatile("" ::: "memory");

    bf16x8 af0[2][2], af1[2][2], bf0[2][2], bf1[2][2];

#pragma unroll
    for (int mi = 0; mi < 2; mi++)
#pragma unroll
      for (int kk = 0; kk < 2; kk++)
        af0[mi][kk] = *(const bf16x8*)(&la[cb][(wr*32 + mi*16 + c15)*64 + (((kk*4 + hi) ^ l7) * 8)]);
#pragma unroll
    for (int ni = 0; ni < 2; ni++)
#pragma unroll
      for (int kk = 0; kk < 2; kk++)
        bf0[ni][kk] = *(const bf16x8*)(&lb[cb][(wc*64 + ni*16 + c15)*64 + (((kk*4 + hi) ^ l7) * 8)]);
    if (t + 1 < NT) STB(nb, t + 1);
    __builtin_amdgcn_s_setprio(1);
#pragma unroll
    for (int mi = 0; mi < 2; mi++)
#pragma unroll
      for (int ni = 0; ni < 2; ni++)
#pragma unroll
        for (int kk = 0; kk < 2; kk++)
          acc[mi][ni] = mfma16(af0[mi][kk], bf0[ni][kk], acc[mi][ni]);
    __builtin_amdgcn_s_setprio(0);

#pragma unroll
    for (int ni = 0; ni < 2; ni++)
#pragma unroll
      for (int kk = 0; kk < 2; kk++)
        bf1[ni][kk] = *(const bf16x8*)(&lb[cb][(wc*64 + 32 + ni*16 + c15)*64 + (((kk*4 + hi) ^ l7) * 8)]);
    if (t + 1 < NT) STA(nb, 0, t + 1);
    __builtin_amdgcn_s_setprio(1);
#pragma unroll
    for (int mi = 0; mi < 2; mi++)
#pragma unroll
      for (int ni = 0; ni < 2; ni++)
#pragma unroll
        for (int kk = 0; kk < 2; kk++)
          acc[mi][2 + ni] = mfma16(af0[mi][kk], bf1[ni][kk], acc[mi][2 + ni]);
    __builtin_amdgcn_s_setprio(0);

    if (t + 1 < NT) { asm volatile("s_waitcnt vmcnt(4)" ::: "memory"); }
    else            { asm volatile("s_waitcnt vmcnt(0)" ::: "memory"); }
    __builtin_amdgcn_s_barrier();
    asm volatile("" ::: "memory");

#pragma unroll
    for (int mi = 0; mi < 2; mi++)
#pragma unroll
      for (int kk = 0; kk < 2; kk++)
        af1[mi][kk] = *(const bf16x8*)(&la[cb][(128 + wr*32 + mi*16 + c15)*64 + (((kk*4 + hi) ^ l7) * 8)]);
    if (t + 1 < NT) STA(nb, 1, t + 1);
    __builtin_amdgcn_s_setprio(1);
#pragma unroll
    for (int mi = 0; mi < 2; mi++)
#pragma unroll
      for (int ni = 0; ni < 2; ni++)
#pragma unroll
        for (int kk = 0; kk < 2; kk++)
          acc[2 + mi][2 + ni] = mfma16(af1[mi][kk], bf1[ni][kk], acc[2 + mi][2 + ni]);
    __builtin_amdgcn_s_setprio(0);

    __builtin_amdgcn_s_setprio(1);
#pragma unroll
    for (int mi = 0; mi < 2; mi++)
#pragma unroll
      for (int ni = 0; ni < 2; ni++)
#pragma unroll
        for (int kk = 0; kk < 2; kk++)
          acc[2 + mi][ni] = mfma16(af1[mi][kk], bf0[ni][kk], acc[2 + mi][ni]);
    __builtin_amdgcn_s_setprio(0);
  }
#undef STA
#undef STB

#pragma unroll
  for (int mi = 0; mi < 4; mi++) {
    int rbase = m0 + ((mi < 2) ? (wr*32 + mi*16) : (128 + wr*32 + (mi - 2)*16)) + hi*4;
#pragma unroll
    for (int ni = 0; ni < 4; ni++) {
      int n  = n0 + wc*64 + ni*16 + c15;
      int cz = n & 1023;
      float bvv = bias[cz];
      int h = cz >> 6, d = cz & 63;
      int b = rbase >> 11, s = rbase & 2047;
      if (z < 2) {
        bf16* C = z ? Kb : Qb;
        float sc = z ? 1.0f : QSCALE;
#pragma unroll
        for (int r = 0; r < 4; r++)
          C[((b*NH + h)*SEQ + (s + r))*HD + d] = (bf16)((acc[mi][ni][r] + bvv) * sc);
      } else {
        bf16x4 o;
#pragma unroll
        for (int r = 0; r < 4; r++) o[r] = (bf16)(acc[mi][ni][r] + bvv);
        *(bf16x4*)(Vtb + ((size_t)(b*NH + h)*HD + d)*SEQ + s) = o;
      }
    }
  }
}

// Output GEMM on the same skeleton: float C[8192,1024] = ctx @ Wo^T + bo.
// Grid 256 = 32 by x 8 bx = exactly 1 block/CU.
__global__ __launch_bounds__(512, 2) void gemm_out256(
    const bf16* __restrict__ A, const bf16* __restrict__ W,
    const float* __restrict__ bias, float* __restrict__ C)
{
  __shared__ __align__(16) bf16 la[2][256*64];
  __shared__ __align__(16) bf16 lb[2][128*64];

  const int K = 1024;
  int tid = threadIdx.x, wid = tid >> 6, lane = tid & 63;
  int wr = wid >> 1, wc = wid & 1;
  int c15 = lane & 15, hi = lane >> 4, l7 = lane & 7;

  int orig = blockIdx.x;
  int xcd = orig & 7, j = orig >> 3;             // j in 0..31
  int by = xcd * 4 + (j & 3);
  int bx = j >> 2;                               // 0..7
  int m0 = by * 256, n0 = bx * 128;

  int r8 = lane >> 3;
  int cu = (lane & 7) ^ r8;

  const bf16* gA = A + (size_t)m0 * K;
  const bf16* gW = W + (size_t)n0 * K;

#define STA(buf, h, kt)                                                        \
  {                                                                            \
    _Pragma("unroll")                                                          \
    for (int op = 0; op < 2; op++) {                                           \
      int rowl = (h)*128 + wid*16 + op*8 + r8;                                 \
      gload16(&la[buf][((h)*128 + wid*16 + op*8)*64],                          \
              gA + (size_t)rowl*K + (kt)*64 + cu*8);                           \
    }                                                                          \
  }
#define STB(buf, kt)                                                           \
  {                                                                            \
    _Pragma("unroll")                                                          \
    for (int op = 0; op < 2; op++) {                                           \
      int rowl = wid*16 + op*8 + r8;                                           \
      gload16(&lb[buf][(wid*16 + op*8)*64],                                    \
              gW + (size_t)rowl*K + (kt)*64 + cu*8);                           \
    }                                                                          \
  }

  f32x4 acc[4][4] = {};
  const int NT = K / 64;

  STB(0, 0);
  STA(0, 0, 0);
  STA(0, 1, 0);

  for (int t = 0; t < NT; ++t) {
    int cb = t & 1, nb = cb ^ 1;
    asm volatile("s_waitcnt vmcnt(2)" ::: "memory");
    __builtin_amdgcn_s_barrier();
    asm volatile("" ::: "memory");

    bf16x8 af0[2][2], af1[2][2], bf0[2][2], bf1[2][2];

#pragma unroll
    for (int mi = 0; mi < 2; mi++)
#pragma unroll
      for (int kk = 0; kk < 2; kk++)
        af0[mi][kk] = *(const bf16x8*)(&la[cb][(wr*32 + mi*16 + c15)*64 + (((kk*4 + hi) ^ l7) * 8)]);
#pragma unroll
    for (int ni = 0; ni < 2; ni++)
#pragma unroll
      for (int kk = 0; kk < 2; kk++)
        bf0[ni][kk] = *(const bf16x8*)(&lb[cb][(wc*64 + ni*16 + c15)*64 + (((kk*4 + hi) ^ l7) * 8)]);
    if (t + 1 < NT) STB(nb, t + 1);
    __builtin_amdgcn_s_setprio(1);
#pragma unroll
    for (int mi = 0; mi < 2; mi++)
#pragma unroll
      for (int ni = 0; ni < 2; ni++)
#pragma unroll
        for (int kk = 0; kk < 2; kk++)
          acc[mi][ni] = mfma16(af0[mi][kk], bf0[ni][kk], acc[mi][ni]);
    __builtin_amdgcn_s_setprio(0);

#pragma unroll
    for (int ni = 0; ni < 2; ni++)
#pragma unroll
      for (int kk = 0; kk < 2; kk++)
        bf1[ni][kk] = *(const bf16x8*)(&lb[cb][(wc*64 + 32 + ni*16 + c15)*64 + (((kk*4 + hi) ^ l7) * 8)]);
    if (t + 1 < NT) STA(nb, 0, t + 1);
    __builtin_amdgcn_s_setprio(1);
#pragma unroll
    for (int mi = 0; mi < 2; mi++)
#pragma unroll
      for (int ni = 0; ni < 2; ni++)
#pragma unroll
        for (int kk = 0; kk < 2; kk++)
          acc[mi][2 + ni] = mfma16(af0[mi][kk], bf1[ni][kk], acc[mi][2 + ni]);
    __builtin_amdgcn_s_setprio(0);

    if (t + 1 < NT) { asm volatile("s_waitcnt vmcnt(4)" ::: "memory"); }
    else            { asm volatile("s_waitcnt vmcnt(0)" ::: "memory"); }
    __builtin_amdgcn_s_barrier();
    asm volatile("" ::: "memory");

#pragma unroll
    for (int mi = 0; mi < 2; mi++)
#pragma unroll
      for (int kk = 0; kk < 2; kk++)
        af1[mi][kk] = *(const bf16x8*)(&la[cb][(128 + wr*32 + mi*16 + c15)*64 + (((kk*4 + hi) ^ l7) * 8)]);
    if (t + 1 < NT) STA(nb, 1, t + 1);
    __builtin_amdgcn_s_setprio(1);
#pragma unroll
    for (int mi = 0; mi < 2; mi++)
#pragma unroll
      for (int ni = 0; ni < 2; ni++)
#pragma unroll
        for (int kk = 0; kk < 2; kk++)
          acc[2 + mi][2 + ni] = mfma16(af1[mi][kk], bf1[ni][kk], acc[2 + mi][2 + ni]);
    __builtin_amdgcn_s_setprio(0);

    __builtin_amdgcn_s_setprio(1);
#pragma unroll
    for (int mi = 0; mi < 2; mi++)
#pragma unroll
      for (int ni = 0; ni < 2; ni++)
#pragma unroll
        for (int kk = 0; kk < 2; kk++)
          acc[2 + mi][ni] = mfma16(af1[mi][kk], bf0[ni][kk], acc[2 + mi][ni]);
    __builtin_amdgcn_s_setprio(0);
  }
#undef STA
#undef STB

#pragma unroll
  for (int mi = 0; mi < 4; mi++) {
    int rbase = m0 + ((mi < 2) ? (wr*32 + mi*16) : (128 + wr*32 + (mi - 2)*16)) + hi*4;
#pragma unroll
    for (int ni = 0; ni < 4; ni++) {
      int col = n0 + wc*64 + ni*16 + c15;
      float bvv = bias[col];
#pragma unroll
      for (int r = 0; r < 4; r++)
        C[(size_t)(rbase + r)*DM + col] = acc[mi][ni][r] + bvv;
    }
  }
}

// Flash attention v10: v5 per-wave body (2 q-tiles, qt-shared LDS reads,
// posum-MFMA normalizer) at 2-wave blocks, KVBLK=64, LDS 32KB ->
// 4 blocks/CU x 2 waves = 4 waves/SIMD (2x wave interleave vs v5, no lockstep).
__global__ __launch_bounds__(128, 4) void attn(
    const bf16* __restrict__ Q, const bf16* __restrict__ Kin,
    const bf16* __restrict__ Vt, bf16* __restrict__ ctx)
{
  __shared__ __align__(16) bf16 kt[2][64*64];   // [kv][d], 16B-unit swz: c8 ^= (kv&7)
  __shared__ __align__(16) bf16 vt[2][64*64];   // [d][kv], same swizzle

  int tid = threadIdx.x, wid = tid >> 6, lane = tid & 63;
  int l31 = lane & 31, hi = lane >> 5, l7 = lane & 7;

  // XCD-chunked swizzle over 1024 blocks: each XCD gets 8 bh (4MB K/V in L2)
  int orig = blockIdx.y * gridDim.x + blockIdx.x;
  int swz  = (orig & 7) * 128 + (orig >> 3);
  int bh   = swz >> 4, q0 = (swz & 15) * 128;

  const bf16* Qp = Q   + (size_t)bh*SEQ*HD;
  const bf16* Kp = Kin + (size_t)bh*SEQ*HD;
  const bf16* Vp = Vt  + (size_t)bh*HD*SEQ;
  int qw = q0 + wid*64;                    // wave's 64 q rows (2 tiles of 32)

  bf16x8 qf[2][4];
#pragma unroll
  for (int qt = 0; qt < 2; qt++)
#pragma unroll
    for (int dblk = 0; dblk < 4; dblk++)
      qf[qt][dblk] = *(const bf16x8*)(Qp + (size_t)(qw + qt*32 + l31)*HD + dblk*16 + hi*8);

  f32x16 po[2][2]  = {};                   // [qt][dt]
  f32x16 posum[2]  = {};                   // [qt] row sums via MFMA (B=ones)

  bf16x8 onesv;
#pragma unroll
  for (int j = 0; j < 8; j++) onesv[j] = (bf16)1.0f;

  int r8 = lane >> 3;
  int c16s = (lane & 7) ^ r8;              // pre-swizzled source 16B-unit

#define STAGE(buf, kv0)                                                        \
  {                                                                            \
    _Pragma("unroll")                                                          \
    for (int op = 0; op < 4; op++) {                                           \
      int rowl = wid*32 + op*8 + r8;                                           \
      gload16(&kt[buf][(wid*32 + op*8)*64], Kp + (size_t)((kv0) + rowl)*HD + c16s*8); \
      gload16(&vt[buf][(wid*32 + op*8)*64], Vp + (size_t)rowl*SEQ + (kv0) + c16s*8);  \
    }                                                                          \
  }

  STAGE(0, 0);
  __syncthreads();

  for (int it = 0; it < SEQ/64; ++it) {
    int cur = it & 1;
    if (it < SEQ/64 - 1) STAGE(cur ^ 1, (it + 1) * 64);

    // ---- S^T = K·Q^T, both q-tiles share each kf read
    f32x16 st[2][2] = {};                  // [qt][kvt]
    __builtin_amdgcn_s_setprio(1);
#pragma unroll
    for (int kvt = 0; kvt < 2; kvt++) {
      int rowb = (kvt*32 + l31) * 64;      // row&7 == l7
#pragma unroll
      for (int dblk = 0; dblk < 4; dblk++) {
        bf16x8 kf = *(const bf16x8*)(&kt[cur][rowb + (((dblk*2 + hi) ^ l7) * 8)]);
        st[0][kvt] = mfma32(kf, qf[0][dblk], st[0][kvt]);
        st[1][kvt] = mfma32(kf, qf[1][dblk], st[1][kvt]);
      }
    }
    __builtin_amdgcn_s_setprio(0);

    // ---- P = exp2(S) raw; pack to PV A-fragments
    bf16x8 pa[2][2][2];                    // [qt][kvt][cp]
#pragma unroll
    for (int qt = 0; qt < 2; qt++) {
#pragma unroll
      for (int kvt = 0; kvt < 2; kvt++)
#pragma unroll
        for (int i = 0; i < 16; i++)
          st[qt][kvt][i] = exp2a(st[qt][kvt][i]);
#pragma unroll
      for (int kvt = 0; kvt < 2; kvt++)
#pragma unroll
        for (int cp = 0; cp < 2; cp++) {
          int m0 = 2*cp, m1 = 2*cp + 1;
          unsigned w0a = cvtpk(st[qt][kvt][4*m0+0], st[qt][kvt][4*m0+1]);
          unsigned w1a = cvtpk(st[qt][kvt][4*m0+2], st[qt][kvt][4*m0+3]);
          unsigned w0b = cvtpk(st[qt][kvt][4*m1+0], st[qt][kvt][4*m1+1]);
          unsigned w1b = cvtpk(st[qt][kvt][4*m1+2], st[qt][kvt][4*m1+3]);
          asm("v_permlane32_swap_b32 %0, %1" : "+v"(w0a), "+v"(w0b));
          asm("v_permlane32_swap_b32 %0, %1" : "+v"(w1a), "+v"(w1b));
          pa[qt][kvt][cp] = __builtin_bit_cast(bf16x8, (u32x4v){w0a, w1a, w0b, w1b});
        }
    }

    // ---- PV + MFMA row-sums (both q-tiles share each vf read)
    __builtin_amdgcn_s_setprio(1);
#pragma unroll
    for (int dt = 0; dt < 2; dt++) {
      int rowb = (dt*32 + l31) * 64;       // row&7 == l7
#pragma unroll
      for (int c = 0; c < 4; c++) {
        bf16x8 vf = *(const bf16x8*)(&vt[cur][rowb + (((c*2 + hi) ^ l7) * 8)]);
        po[0][dt] = mfma32(pa[0][c >> 1][c & 1], vf, po[0][dt]);
        po[1][dt] = mfma32(pa[1][c >> 1][c & 1], vf, po[1][dt]);
      }
    }
#pragma unroll
    for (int c = 0; c < 4; c++) {
      posum[0] = mfma32(pa[0][c >> 1][c & 1], onesv, posum[0]);
      posum[1] = mfma32(pa[1][c >> 1][c & 1], onesv, posum[1]);
    }
    __builtin_amdgcn_s_setprio(0);

    __syncthreads();   // drains vmcnt for next tile + WAR on buf[cur]
  }
#undef STAGE

  // ---- epilogue: normalize by MFMA-accumulated row sums (no shuffles)
  int b = bh >> 4, h = bh & 15;
#pragma unroll
  for (int qt = 0; qt < 2; qt++)
#pragma unroll
    for (int reg = 0; reg < 16; reg++) {
      int qq = (reg & 3) + 8*(reg >> 2) + 4*hi;
      float inv = 1.0f / posum[qt][reg];
      int s = qw + qt*32 + qq;
      bf16* dst = ctx + (size_t)(b*SEQ + s)*DM + h*HD + l31;
      dst[0]  = (bf16)(po[qt][0][reg] * inv);
      dst[32] = (bf16)(po[qt][1][reg] * inv);
    }
}

extern "C" void kernel_launch(void* const* d_in, const int* in_sizes, int n_in,
                              void* d_out, int out_size, void* d_ws, size_t ws_size,
                              hipStream_t stream)
{
  const float* x  = (const float*)d_in[0];
  const float* Wq = (const float*)d_in[1];
  const float* bq = (const float*)d_in[2];
  const float* Wk = (const float*)d_in[3];
  const float* bk = (const float*)d_in[4];
  const float* Wv = (const float*)d_in[5];
  const float* bv = (const float*)d_in[6];
  const float* Wo = (const float*)d_in[7];
  const float* bo = (const float*)d_in[8];

  bf16* ws  = (bf16*)d_ws;
  bf16* xb  = ws;                          // [8192][1024] bf16 x
  bf16* Wb  = ws + ELEMS;                  // 4 x [1024][1024] bf16 weights (q,k,v,o)
  bf16* Qb  = ws + ELEMS + 4*WELEMS;       // [B,H,S,hd] (pre-scaled)
  bf16* Kb  = Qb + ELEMS;
  bf16* Vtb = Kb + ELEMS;                  // [B,H,hd,S]
  bf16* ctx = xb;                          // reuse x slot (dead after projections)

  cvt_all<<<dim3(ELEMS/1024, 5), dim3(256), 0, stream>>>(x, xb, Wq, Wk, Wv, Wo, Wb);
  gemm_qkv256<<<dim3(768), dim3(512), 0, stream>>>(
      xb, Wb, bq, bk, bv, Qb, Kb, Vtb);
  attn<<<dim3(SEQ/128, BHN), dim3(128), 0, stream>>>(Qb, Kb, Vtb, ctx);
  gemm_out256<<<dim3(256), dim3(512), 0, stream>>>(
      ctx, Wb + 3*WELEMS, bo, (float*)d_out);
}

// Round 14
// 179.042 us; speedup vs baseline: 1.2338x; 1.2338x over previous
//
#include <hip/hip_runtime.h>

typedef __bf16 bf16;
typedef __bf16 bf16x4 __attribute__((ext_vector_type(4)));
typedef __bf16 bf16x8 __attribute__((ext_vector_type(8)));
typedef float  f32x4  __attribute__((ext_vector_type(4)));
typedef float  f32x16 __attribute__((ext_vector_type(16)));
typedef unsigned int u32x4v __attribute__((ext_vector_type(4)));

#define NB   4
#define SEQ  2048
#define DM   1024
#define NH   16
#define HD   64
#define BHN  (NB*NH)       // 64
#define MTOT (NB*SEQ)      // 8192
#define ELEMS ((size_t)MTOT*DM)  // 8388608
#define WELEMS (DM*DM)     // 1048576
#define QSCALE 0.18033688011112042f   // 0.125 * log2(e): scores in log2 units

__device__ __forceinline__ void gload16(void* lds, const void* g) {
  __builtin_amdgcn_global_load_lds(
      (const __attribute__((address_space(1))) void*)g,
      (__attribute__((address_space(3))) void*)lds, 16, 0, 0);
}

__device__ __forceinline__ f32x4 mfma16(bf16x8 a, bf16x8 b, f32x4 c) {
  return __builtin_amdgcn_mfma_f32_16x16x32_bf16(a, b, c, 0, 0, 0);
}
__device__ __forceinline__ f32x16 mfma32(bf16x8 a, bf16x8 b, f32x16 c) {
  return __builtin_amdgcn_mfma_f32_32x32x16_bf16(a, b, c, 0, 0, 0);
}
__device__ __forceinline__ unsigned cvtpk(float lo, float hi) {
  unsigned r;
  asm("v_cvt_pk_bf16_f32 %0, %1, %2" : "=v"(r) : "v"(lo), "v"(hi));
  return r;
}
__device__ __forceinline__ float exp2a(float x) {   // D = 2^x
  float r;
  asm("v_exp_f32 %0, %1" : "=v"(r) : "v"(x));
  return r;
}

// fp32 -> bf16 conversion: y=0..3 -> W_y, y=4 -> x
__global__ __launch_bounds__(256) void cvt_all(
    const float* __restrict__ x, bf16* __restrict__ xb,
    const float* __restrict__ w0, const float* __restrict__ w1,
    const float* __restrict__ w2, const float* __restrict__ w3,
    bf16* __restrict__ wb)
{
  int y = blockIdx.y;
  const float* src; bf16* dst; int nblk;
  if (y < 4) {
    src = (y == 0) ? w0 : (y == 1) ? w1 : (y == 2) ? w2 : w3;
    dst = wb + (size_t)y * WELEMS;
    nblk = WELEMS / 1024;
  } else {
    src = x; dst = xb; nblk = (int)(ELEMS / 1024);
  }
  if (blockIdx.x >= nblk) return;
  int i = blockIdx.x * 1024 + threadIdx.x * 4;
  f32x4 v = *(const f32x4*)(src + i);
  bf16x4 o;
#pragma unroll
  for (int j = 0; j < 4; j++) o[j] = (bf16)v[j];
  *(bf16x4*)(dst + i) = o;
}

// ============ 256x128 4-phase counted-vmcnt GEMM skeleton (proven r12/r13) ==

// Fused QKV: C[8192,3072] = x @ [Wq|Wk|Wv]^T + bias -> Q/K [B,H,S,hd], Vt [B,H,hd,S]
__global__ __launch_bounds__(512, 2) void gemm_qkv256(
    const bf16* __restrict__ A, const bf16* __restrict__ Wb3,
    const float* __restrict__ bq, const float* __restrict__ bk,
    const float* __restrict__ bv,
    bf16* __restrict__ Qb, bf16* __restrict__ Kb, bf16* __restrict__ Vtb)
{
  __shared__ __align__(16) bf16 la[2][256*64];   // A tile [row][k], swz u^=(row&7)
  __shared__ __align__(16) bf16 lb[2][128*64];   // W tile [row][k], same swz

  const int K = 1024;
  int tid = threadIdx.x, wid = tid >> 6, lane = tid & 63;
  int wr = wid >> 1, wc = wid & 1;               // 4M x 2N wave grid
  int c15 = lane & 15, hi = lane >> 4, l7 = lane & 7;

  // XCD map: XCD owns 4 contiguous by (2MB A, L2-resident); by fastest.
  int orig = blockIdx.x;
  int xcd = orig & 7, j = orig >> 3;             // j in 0..95
  int by = xcd * 4 + (j & 3);
  int bx = j >> 2;
  int m0 = by * 256, n0 = bx * 128;
  int z  = n0 >> 10;                             // 0=Q 1=K 2=V
  const float* bias = (z == 0) ? bq : (z == 1) ? bk : bv;

  int r8 = lane >> 3;
  int cu = (lane & 7) ^ r8;

  const bf16* gA = A   + (size_t)m0 * K;
  const bf16* gW = Wb3 + (size_t)n0 * K;

#define STA(buf, h, kt)                                                        \
  {                                                                            \
    _Pragma("unroll")                                                          \
    for (int op = 0; op < 2; op++) {                                           \
      int rowl = (h)*128 + wid*16 + op*8 + r8;                                 \
      gload16(&la[buf][((h)*128 + wid*16 + op*8)*64],                          \
              gA + (size_t)rowl*K + (kt)*64 + cu*8);                           \
    }                                                                          \
  }
#define STB(buf, kt)                                                           \
  {                                                                            \
    _Pragma("unroll")                                                          \
    for (int op = 0; op < 2; op++) {                                           \
      int rowl = wid*16 + op*8 + r8;                                           \
      gload16(&lb[buf][(wid*16 + op*8)*64],                                    \
              gW + (size_t)rowl*K + (kt)*64 + cu*8);                           \
    }                                                                          \
  }

  f32x4 acc[4][4] = {};
  const int NT = K / 64;                         // 16

  STB(0, 0);
  STA(0, 0, 0);
  STA(0, 1, 0);

  for (int t = 0; t < NT; ++t) {
    int cb = t & 1, nb = cb ^ 1;
    asm volatile("s_waitcnt vmcnt(2)" ::: "memory");
    __builtin_amdgcn_s_barrier();
    asm volatile("" ::: "memory");

    bf16x8 af0[2][2], af1[2][2], bf0[2][2], bf1[2][2];

#pragma unroll
    for (int mi = 0; mi < 2; mi++)
#pragma unroll
      for (int kk = 0; kk < 2; kk++)
        af0[mi][kk] = *(const bf16x8*)(&la[cb][(wr*32 + mi*16 + c15)*64 + (((kk*4 + hi) ^ l7) * 8)]);
#pragma unroll
    for (int ni = 0; ni < 2; ni++)
#pragma unroll
      for (int kk = 0; kk < 2; kk++)
        bf0[ni][kk] = *(const bf16x8*)(&lb[cb][(wc*64 + ni*16 + c15)*64 + (((kk*4 + hi) ^ l7) * 8)]);
    if (t + 1 < NT) STB(nb, t + 1);
    __builtin_amdgcn_s_setprio(1);
#pragma unroll
    for (int mi = 0; mi < 2; mi++)
#pragma unroll
      for (int ni = 0; ni < 2; ni++)
#pragma unroll
        for (int kk = 0; kk < 2; kk++)
          acc[mi][ni] = mfma16(af0[mi][kk], bf0[ni][kk], acc[mi][ni]);
    __builtin_amdgcn_s_setprio(0);

#pragma unroll
    for (int ni = 0; ni < 2; ni++)
#pragma unroll
      for (int kk = 0; kk < 2; kk++)
        bf1[ni][kk] = *(const bf16x8*)(&lb[cb][(wc*64 + 32 + ni*16 + c15)*64 + (((kk*4 + hi) ^ l7) * 8)]);
    if (t + 1 < NT) STA(nb, 0, t + 1);
    __builtin_amdgcn_s_setprio(1);
#pragma unroll
    for (int mi = 0; mi < 2; mi++)
#pragma unroll
      for (int ni = 0; ni < 2; ni++)
#pragma unroll
        for (int kk = 0; kk < 2; kk++)
          acc[mi][2 + ni] = mfma16(af0[mi][kk], bf1[ni][kk], acc[mi][2 + ni]);
    __builtin_amdgcn_s_setprio(0);

    if (t + 1 < NT) { asm volatile("s_waitcnt vmcnt(4)" ::: "memory"); }
    else            { asm volatile("s_waitcnt vmcnt(0)" ::: "memory"); }
    __builtin_amdgcn_s_barrier();
    asm volatile("" ::: "memory");

#pragma unroll
    for (int mi = 0; mi < 2; mi++)
#pragma unroll
      for (int kk = 0; kk < 2; kk++)
        af1[mi][kk] = *(const bf16x8*)(&la[cb][(128 + wr*32 + mi*16 + c15)*64 + (((kk*4 + hi) ^ l7) * 8)]);
    if (t + 1 < NT) STA(nb, 1, t + 1);
    __builtin_amdgcn_s_setprio(1);
#pragma unroll
    for (int mi = 0; mi < 2; mi++)
#pragma unroll
      for (int ni = 0; ni < 2; ni++)
#pragma unroll
        for (int kk = 0; kk < 2; kk++)
          acc[2 + mi][2 + ni] = mfma16(af1[mi][kk], bf1[ni][kk], acc[2 + mi][2 + ni]);
    __builtin_amdgcn_s_setprio(0);

    __builtin_amdgcn_s_setprio(1);
#pragma unroll
    for (int mi = 0; mi < 2; mi++)
#pragma unroll
      for (int ni = 0; ni < 2; ni++)
#pragma unroll
        for (int kk = 0; kk < 2; kk++)
          acc[2 + mi][ni] = mfma16(af1[mi][kk], bf0[ni][kk], acc[2 + mi][ni]);
    __builtin_amdgcn_s_setprio(0);
  }
#undef STA
#undef STB

#pragma unroll
  for (int mi = 0; mi < 4; mi++) {
    int rbase = m0 + ((mi < 2) ? (wr*32 + mi*16) : (128 + wr*32 + (mi - 2)*16)) + hi*4;
#pragma unroll
    for (int ni = 0; ni < 4; ni++) {
      int n  = n0 + wc*64 + ni*16 + c15;
      int cz = n & 1023;
      float bvv = bias[cz];
      int h = cz >> 6, d = cz & 63;
      int b = rbase >> 11, s = rbase & 2047;
      if (z < 2) {
        bf16* C = z ? Kb : Qb;
        float sc = z ? 1.0f : QSCALE;
#pragma unroll
        for (int r = 0; r < 4; r++)
          C[((b*NH + h)*SEQ + (s + r))*HD + d] = (bf16)((acc[mi][ni][r] + bvv) * sc);
      } else {
        bf16x4 o;
#pragma unroll
        for (int r = 0; r < 4; r++) o[r] = (bf16)(acc[mi][ni][r] + bvv);
        *(bf16x4*)(Vtb + ((size_t)(b*NH + h)*HD + d)*SEQ + s) = o;
      }
    }
  }
}

// Output GEMM on the same skeleton: float C[8192,1024] = ctx @ Wo^T + bo.
__global__ __launch_bounds__(512, 2) void gemm_out256(
    const bf16* __restrict__ A, const bf16* __restrict__ W,
    const float* __restrict__ bias, float* __restrict__ C)
{
  __shared__ __align__(16) bf16 la[2][256*64];
  __shared__ __align__(16) bf16 lb[2][128*64];

  const int K = 1024;
  int tid = threadIdx.x, wid = tid >> 6, lane = tid & 63;
  int wr = wid >> 1, wc = wid & 1;
  int c15 = lane & 15, hi = lane >> 4, l7 = lane & 7;

  int orig = blockIdx.x;
  int xcd = orig & 7, j = orig >> 3;             // j in 0..31
  int by = xcd * 4 + (j & 3);
  int bx = j >> 2;                               // 0..7
  int m0 = by * 256, n0 = bx * 128;

  int r8 = lane >> 3;
  int cu = (lane & 7) ^ r8;

  const bf16* gA = A + (size_t)m0 * K;
  const bf16* gW = W + (size_t)n0 * K;

#define STA(buf, h, kt)                                                        \
  {                                                                            \
    _Pragma("unroll")                                                          \
    for (int op = 0; op < 2; op++) {                                           \
      int rowl = (h)*128 + wid*16 + op*8 + r8;                                 \
      gload16(&la[buf][((h)*128 + wid*16 + op*8)*64],                          \
              gA + (size_t)rowl*K + (kt)*64 + cu*8);                           \
    }                                                                          \
  }
#define STB(buf, kt)                                                           \
  {                                                                            \
    _Pragma("unroll")                                                          \
    for (int op = 0; op < 2; op++) {                                           \
      int rowl = wid*16 + op*8 + r8;                                           \
      gload16(&lb[buf][(wid*16 + op*8)*64],                                    \
              gW + (size_t)rowl*K + (kt)*64 + cu*8);                           \
    }                                                                          \
  }

  f32x4 acc[4][4] = {};
  const int NT = K / 64;

  STB(0, 0);
  STA(0, 0, 0);
  STA(0, 1, 0);

  for (int t = 0; t < NT; ++t) {
    int cb = t & 1, nb = cb ^ 1;
    asm volatile("s_waitcnt vmcnt(2)" ::: "memory");
    __builtin_amdgcn_s_barrier();
    asm volatile("" ::: "memory");

    bf16x8 af0[2][2], af1[2][2], bf0[2][2], bf1[2][2];

#pragma unroll
    for (int mi = 0; mi < 2; mi++)
#pragma unroll
      for (int kk = 0; kk < 2; kk++)
        af0[mi][kk] = *(const bf16x8*)(&la[cb][(wr*32 + mi*16 + c15)*64 + (((kk*4 + hi) ^ l7) * 8)]);
#pragma unroll
    for (int ni = 0; ni < 2; ni++)
#pragma unroll
      for (int kk = 0; kk < 2; kk++)
        bf0[ni][kk] = *(const bf16x8*)(&lb[cb][(wc*64 + ni*16 + c15)*64 + (((kk*4 + hi) ^ l7) * 8)]);
    if (t + 1 < NT) STB(nb, t + 1);
    __builtin_amdgcn_s_setprio(1);
#pragma unroll
    for (int mi = 0; mi < 2; mi++)
#pragma unroll
      for (int ni = 0; ni < 2; ni++)
#pragma unroll
        for (int kk = 0; kk < 2; kk++)
          acc[mi][ni] = mfma16(af0[mi][kk], bf0[ni][kk], acc[mi][ni]);
    __builtin_amdgcn_s_setprio(0);

#pragma unroll
    for (int ni = 0; ni < 2; ni++)
#pragma unroll
      for (int kk = 0; kk < 2; kk++)
        bf1[ni][kk] = *(const bf16x8*)(&lb[cb][(wc*64 + 32 + ni*16 + c15)*64 + (((kk*4 + hi) ^ l7) * 8)]);
    if (t + 1 < NT) STA(nb, 0, t + 1);
    __builtin_amdgcn_s_setprio(1);
#pragma unroll
    for (int mi = 0; mi < 2; mi++)
#pragma unroll
      for (int ni = 0; ni < 2; ni++)
#pragma unroll
        for (int kk = 0; kk < 2; kk++)
          acc[mi][2 + ni] = mfma16(af0[mi][kk], bf1[ni][kk], acc[mi][2 + ni]);
    __builtin_amdgcn_s_setprio(0);

    if (t + 1 < NT) { asm volatile("s_waitcnt vmcnt(4)" ::: "memory"); }
    else            { asm volatile("s_waitcnt vmcnt(0)" ::: "memory"); }
    __builtin_amdgcn_s_barrier();
    asm volatile("" ::: "memory");

#pragma unroll
    for (int mi = 0; mi < 2; mi++)
#pragma unroll
      for (int kk = 0; kk < 2; kk++)
        af1[mi][kk] = *(const bf16x8*)(&la[cb][(128 + wr*32 + mi*16 + c15)*64 + (((kk*4 + hi) ^ l7) * 8)]);
    if (t + 1 < NT) STA(nb, 1, t + 1);
    __builtin_amdgcn_s_setprio(1);
#pragma unroll
    for (int mi = 0; mi < 2; mi++)
#pragma unroll
      for (int ni = 0; ni < 2; ni++)
#pragma unroll
        for (int kk = 0; kk < 2; kk++)
          acc[2 + mi][2 + ni] = mfma16(af1[mi][kk], bf1[ni][kk], acc[2 + mi][2 + ni]);
    __builtin_amdgcn_s_setprio(0);

    __builtin_amdgcn_s_setprio(1);
#pragma unroll
    for (int mi = 0; mi < 2; mi++)
#pragma unroll
      for (int ni = 0; ni < 2; ni++)
#pragma unroll
        for (int kk = 0; kk < 2; kk++)
          acc[2 + mi][ni] = mfma16(af1[mi][kk], bf0[ni][kk], acc[2 + mi][ni]);
    __builtin_amdgcn_s_setprio(0);
  }
#undef STA
#undef STB

#pragma unroll
  for (int mi = 0; mi < 4; mi++) {
    int rbase = m0 + ((mi < 2) ? (wr*32 + mi*16) : (128 + wr*32 + (mi - 2)*16)) + hi*4;
#pragma unroll
    for (int ni = 0; ni < 4; ni++) {
      int col = n0 + wc*64 + ni*16 + c15;
      float bvv = bias[col];
#pragma unroll
      for (int r = 0; r < 4; r++)
        C[(size_t)(rbase + r)*DM + col] = acc[mi][ni][r] + bvv;
    }
  }
}

// Flash attention v5 (round-7/12 best, verbatim): 2 q-tiles/wave, no-max exp2
// softmax, MFMA row-sums, KVBLK=128 per barrier window, swizzled dbuf LDS.
__global__ __launch_bounds__(256, 2) void attn(
    const bf16* __restrict__ Q, const bf16* __restrict__ Kin,
    const bf16* __restrict__ Vt, bf16* __restrict__ ctx)
{
  __shared__ __align__(16) bf16 kt[2][128*64];  // [kv][d], 16B-unit swz: c8 ^= (kv&7)
  __shared__ __align__(16) bf16 vt[2][64*128];  // [d][kv], 16B-unit swz: c16 ^= (d&7)

  int tid = threadIdx.x, wid = tid >> 6, lane = tid & 63;
  int l31 = lane & 31, hi = lane >> 5, l7 = lane & 7;

  int orig = blockIdx.y * gridDim.x + blockIdx.x;
  int swz  = (orig & 7) * 64 + (orig >> 3);
  int bh   = swz >> 3, q0 = (swz & 7) * 256;

  const bf16* Qp = Q   + (size_t)bh*SEQ*HD;
  const bf16* Kp = Kin + (size_t)bh*SEQ*HD;
  const bf16* Vp = Vt  + (size_t)bh*HD*SEQ;
  int qw = q0 + wid*64;

  bf16x8 qf[2][4];
#pragma unroll
  for (int qt = 0; qt < 2; qt++)
#pragma unroll
    for (int dblk = 0; dblk < 4; dblk++)
      qf[qt][dblk] = *(const bf16x8*)(Qp + (size_t)(qw + qt*32 + l31)*HD + dblk*16 + hi*8);

  f32x16 po[2][2]  = {};
  f32x16 posum[2]  = {};

  bf16x8 onesv;
#pragma unroll
  for (int j = 0; j < 8; j++) onesv[j] = (bf16)1.0f;

  int r8 = lane >> 3;
  int ck = (lane & 7) ^ r8;
  int r16 = lane >> 4, c16v = lane & 15;

#define STAGE(buf, kv0)                                                        \
  {                                                                            \
    _Pragma("unroll")                                                          \
    for (int op = 0; op < 4; op++) {                                           \
      int rk = wid*32 + op*8 + r8;                                             \
      gload16(&kt[buf][(wid*32 + op*8)*64],                                    \
              Kp + (size_t)((kv0) + rk)*HD + ck*8);                            \
      int rv = wid*16 + op*4 + r16;                                            \
      gload16(&vt[buf][(wid*16 + op*4)*128],                                   \
              Vp + (size_t)rv*SEQ + (kv0) + ((c16v ^ (rv & 7))*8));            \
    }                                                                          \
  }

  STAGE(0, 0);
  __syncthreads();

  for (int it = 0; it < SEQ/128; ++it) {
    int cur = it & 1;
    if (it < SEQ/128 - 1) STAGE(cur ^ 1, (it + 1) * 128);

#pragma unroll
    for (int sub = 0; sub < 2; sub++) {
      f32x16 st[2][2] = {};
      __builtin_amdgcn_s_setprio(1);
#pragma unroll
      for (int kvt = 0; kvt < 2; kvt++) {
        int rowb = (sub*64 + kvt*32 + l31) * 64;
#pragma unroll
        for (int dblk = 0; dblk < 4; dblk++) {
          bf16x8 kf = *(const bf16x8*)(&kt[cur][rowb + (((dblk*2 + hi) ^ l7) * 8)]);
          st[0][kvt] = mfma32(kf, qf[0][dblk], st[0][kvt]);
          st[1][kvt] = mfma32(kf, qf[1][dblk], st[1][kvt]);
        }
      }
      __builtin_amdgcn_s_setprio(0);

      bf16x8 pa[2][2][2];
#pragma unroll
      for (int qt = 0; qt < 2; qt++) {
#pragma unroll
        for (int kvt = 0; kvt < 2; kvt++)
#pragma unroll
          for (int i = 0; i < 16; i++)
            st[qt][kvt][i] = exp2a(st[qt][kvt][i]);
#pragma unroll
        for (int kvt = 0; kvt < 2; kvt++)
#pragma unroll
          for (int cp = 0; cp < 2; cp++) {
            int m0 = 2*cp, m1 = 2*cp + 1;
            unsigned w0a = cvtpk(st[qt][kvt][4*m0+0], st[qt][kvt][4*m0+1]);
            unsigned w1a = cvtpk(st[qt][kvt][4*m0+2], st[qt][kvt][4*m0+3]);
            unsigned w0b = cvtpk(st[qt][kvt][4*m1+0], st[qt][kvt][4*m1+1]);
            unsigned w1b = cvtpk(st[qt][kvt][4*m1+2], st[qt][kvt][4*m1+3]);
            asm("v_permlane32_swap_b32 %0, %1" : "+v"(w0a), "+v"(w0b));
            asm("v_permlane32_swap_b32 %0, %1" : "+v"(w1a), "+v"(w1b));
            pa[qt][kvt][cp] = __builtin_bit_cast(bf16x8, (u32x4v){w0a, w1a, w0b, w1b});
          }
      }

      __builtin_amdgcn_s_setprio(1);
#pragma unroll
      for (int dt = 0; dt < 2; dt++) {
        int rowb = (dt*32 + l31) * 128;
#pragma unroll
        for (int c = 0; c < 4; c++) {
          bf16x8 vf = *(const bf16x8*)(&vt[cur][rowb + ((sub*8 + ((c*2 + hi) ^ l7)) * 8)]);
          po[0][dt] = mfma32(pa[0][c >> 1][c & 1], vf, po[0][dt]);
          po[1][dt] = mfma32(pa[1][c >> 1][c & 1], vf, po[1][dt]);
        }
      }
#pragma unroll
      for (int c = 0; c < 4; c++) {
        posum[0] = mfma32(pa[0][c >> 1][c & 1], onesv, posum[0]);
        posum[1] = mfma32(pa[1][c >> 1][c & 1], onesv, posum[1]);
      }
      __builtin_amdgcn_s_setprio(0);
    }

    __syncthreads();
  }
#undef STAGE

  int b = bh >> 4, h = bh & 15;
#pragma unroll
  for (int qt = 0; qt < 2; qt++)
#pragma unroll
    for (int reg = 0; reg < 16; reg++) {
      int qq = (reg & 3) + 8*(reg >> 2) + 4*hi;
      float inv = 1.0f / posum[qt][reg];
      int s = qw + qt*32 + qq;
      bf16* dst = ctx + (size_t)(b*SEQ + s)*DM + h*HD + l31;
      dst[0]  = (bf16)(po[qt][0][reg] * inv);
      dst[32] = (bf16)(po[qt][1][reg] * inv);
    }
}

extern "C" void kernel_launch(void* const* d_in, const int* in_sizes, int n_in,
                              void* d_out, int out_size, void* d_ws, size_t ws_size,
                              hipStream_t stream)
{
  const float* x  = (const float*)d_in[0];
  const float* Wq = (const float*)d_in[1];
  const float* bq = (const float*)d_in[2];
  const float* Wk = (const float*)d_in[3];
  const float* bk = (const float*)d_in[4];
  const float* Wv = (const float*)d_in[5];
  const float* bv = (const float*)d_in[6];
  const float* Wo = (const float*)d_in[7];
  const float* bo = (const float*)d_in[8];

  bf16* ws  = (bf16*)d_ws;
  bf16* xb  = ws;                          // [8192][1024] bf16 x
  bf16* Wb  = ws + ELEMS;                  // 4 x [1024][1024] bf16 weights (q,k,v,o)
  bf16* Qb  = ws + ELEMS + 4*WELEMS;       // [B,H,S,hd] (pre-scaled)
  bf16* Kb  = Qb + ELEMS;
  bf16* Vtb = Kb + ELEMS;                  // [B,H,hd,S]
  bf16* ctx = xb;                          // reuse x slot (dead after projections)

  cvt_all<<<dim3(ELEMS/1024, 5), dim3(256), 0, stream>>>(x, xb, Wq, Wk, Wv, Wo, Wb);
  gemm_qkv256<<<dim3(768), dim3(512), 0, stream>>>(
      xb, Wb, bq, bk, bv, Qb, Kb, Vtb);
  attn<<<dim3(SEQ/256, BHN), dim3(256), 0, stream>>>(Qb, Kb, Vtb, ctx);
  gemm_out256<<<dim3(256), dim3(512), 0, stream>>>(
      ctx, Wb + 3*WELEMS, bo, (float*)d_out);
}

// Round 15
// 174.816 us; speedup vs baseline: 1.2636x; 1.0242x over previous
//
#include <hip/hip_runtime.h>

typedef __bf16 bf16;
typedef __bf16 bf16x4 __attribute__((ext_vector_type(4)));
typedef __bf16 bf16x8 __attribute__((ext_vector_type(8)));
typedef float  f32x4  __attribute__((ext_vector_type(4)));
typedef float  f32x16 __attribute__((ext_vector_type(16)));
typedef unsigned int u32x2 __attribute__((ext_vector_type(2)));
typedef unsigned int u32x4v __attribute__((ext_vector_type(4)));

#define NB   4
#define SEQ  2048
#define DM   1024
#define NH   16
#define HD   64
#define BHN  (NB*NH)       // 64
#define MTOT (NB*SEQ)      // 8192
#define ELEMS ((size_t)MTOT*DM)  // 8388608
#define WELEMS (DM*DM)     // 1048576
#define QSCALE 0.18033688011112042f   // 0.125 * log2(e): scores in log2 units

__device__ __forceinline__ void gload16(void* lds, const void* g) {
  __builtin_amdgcn_global_load_lds(
      (const __attribute__((address_space(1))) void*)g,
      (__attribute__((address_space(3))) void*)lds, 16, 0, 0);
}

__device__ __forceinline__ f32x4 mfma16(bf16x8 a, bf16x8 b, f32x4 c) {
  return __builtin_amdgcn_mfma_f32_16x16x32_bf16(a, b, c, 0, 0, 0);
}
__device__ __forceinline__ f32x16 mfma32(bf16x8 a, bf16x8 b, f32x16 c) {
  return __builtin_amdgcn_mfma_f32_32x32x16_bf16(a, b, c, 0, 0, 0);
}
__device__ __forceinline__ unsigned cvtpk(float lo, float hi) {
  unsigned r;
  asm("v_cvt_pk_bf16_f32 %0, %1, %2" : "=v"(r) : "v"(lo), "v"(hi));
  return r;
}
__device__ __forceinline__ float exp2a(float x) {   // D = 2^x
  float r;
  asm("v_exp_f32 %0, %1" : "=v"(r) : "v"(x));
  return r;
}

// fp32 -> bf16 conversion, weights only (x is converted inside gemm_qkv256)
__global__ __launch_bounds__(256) void cvt_w(
    const float* __restrict__ w0, const float* __restrict__ w1,
    const float* __restrict__ w2, const float* __restrict__ w3,
    bf16* __restrict__ wb)
{
  int y = blockIdx.y;
  const float* src = (y == 0) ? w0 : (y == 1) ? w1 : (y == 2) ? w2 : w3;
  bf16* dst = wb + (size_t)y * WELEMS;
  int i = blockIdx.x * 1024 + threadIdx.x * 4;
  f32x4 v = *(const f32x4*)(src + i);
  bf16x4 o;
#pragma unroll
  for (int j = 0; j < 4; j++) o[j] = (bf16)v[j];
  *(bf16x4*)(dst + i) = o;
}

// Fused QKV GEMM with in-kernel fp32->bf16 A conversion (reg-staged A,
// T14 pattern; gload_lds can't convert). B (weights) stays gload_lds.
// One barrier per K-tile (A is per-wave reg-staged -> no cross-wave A halves).
// C[8192,3072] = x_f32 @ [Wq|Wk|Wv]_bf16^T + bias -> Q/K [B,H,S,hd], Vt [B,H,hd,S]
__global__ __launch_bounds__(512, 2) void gemm_qkv256(
    const float* __restrict__ Ax, const bf16* __restrict__ Wb3,
    const float* __restrict__ bq, const float* __restrict__ bk,
    const float* __restrict__ bv,
    bf16* __restrict__ Qb, bf16* __restrict__ Kb, bf16* __restrict__ Vtb)
{
  __shared__ __align__(16) bf16 la[2][256*64];   // A tile [row][k], 16B-unit swz u^=(row&7)
  __shared__ __align__(16) bf16 lb[2][128*64];   // W tile [row][k], same swz

  const int K = 1024;
  int tid = threadIdx.x, wid = tid >> 6, lane = tid & 63;
  int wr = wid >> 1, wc = wid & 1;               // 4M x 2N wave grid
  int c15 = lane & 15, hi = lane >> 4, l7 = lane & 7;

  // XCD map: XCD owns 4 contiguous by (A chunk L2-resident); by fastest.
  int orig = blockIdx.x;
  int xcd = orig & 7, j = orig >> 3;             // j in 0..95
  int by = xcd * 4 + (j & 3);
  int bx = j >> 2;
  int m0 = by * 256, n0 = bx * 128;
  int z  = n0 >> 10;                             // 0=Q 1=K 2=V
  const float* bias = (z == 0) ? bq : (z == 1) ? bk : bv;

  int r8 = lane >> 3;
  int cu = (lane & 7) ^ r8;                      // B pre-swizzled source 16B unit

  const float* gA = Ax  + (size_t)m0 * K;        // fp32 A
  const bf16*  gW = Wb3 + (size_t)n0 * K;

  // A reg-staging geometry: load i covers rows wid*32+i*4+(lane>>4),
  // f32 k-offset (lane&15)*4 (16B, fully coalesced per instruction).
  int arow_lo = lane >> 4;                       // 0..3 within 4-row group
  int acol4   = (lane & 15) * 4;                 // f32 index within 64-wide k
  int k2      = (lane & 15) >> 1;                // 16B unit within row (bf16)
  int ksub    = lane & 1;                        // 8B half of the unit

#define LDA(kt)                                                                \
  {                                                                            \
    _Pragma("unroll")                                                          \
    for (int i = 0; i < 8; i++)                                                \
      areg[i] = *(const f32x4*)(gA + (size_t)(wid*32 + i*4 + arow_lo)*K        \
                                  + (kt)*64 + acol4);                          \
  }
  // cvt + swizzled ds_write_b64 (write-side k2^(row&7) == read-side unit^l7)
#define CVTWR(buf)                                                             \
  {                                                                            \
    _Pragma("unroll")                                                          \
    for (int i = 0; i < 8; i++) {                                              \
      int row = wid*32 + i*4 + arow_lo;                                        \
      u32x2 w = { cvtpk(areg[i][0], areg[i][1]),                               \
                  cvtpk(areg[i][2], areg[i][3]) };                             \
      *(u32x2*)(&la[buf][row*64 + ((k2 ^ (row & 7)) * 8) + ksub*4]) = w;       \
    }                                                                          \
  }
#define STB(buf, kt)                                                           \
  {                                                                            \
    _Pragma("unroll")                                                          \
    for (int op = 0; op < 2; op++) {                                           \
      int rowl = wid*16 + op*8 + r8;                                           \
      gload16(&lb[buf][(wid*16 + op*8)*64],                                    \
              gW + (size_t)rowl*K + (kt)*64 + cu*8);                           \
    }                                                                          \
  }

  f32x4 areg[8];
  f32x4 acc[4][4] = {};                          // [mi][ni]; mi<2 half0, mi>=2 half1
  const int NT = K / 64;                         // 16

  // prologue: tile0 A cvt+write, B gload; tile1 A loads in flight
  LDA(0);                                        // 8 outstanding (auto-wait on use)
  CVTWR(0);
  STB(0, 0);                                     // +2
  LDA(1);                                        // +8 -> 10
  asm volatile("s_waitcnt vmcnt(8)" ::: "memory");   // B(0) landed
  asm volatile("s_waitcnt lgkmcnt(0)" ::: "memory"); // la[0] writes drained
  __builtin_amdgcn_s_barrier();
  asm volatile("" ::: "memory");

  for (int t = 0; t < NT; ++t) {
    int cb = t & 1, nb = cb ^ 1;
    // entry: la[cb], lb[cb] ready+visible; outstanding: areg(t+1) x8

    bf16x8 af0[2][2], af1[2][2], bf0[2][2], bf1[2][2];

    // ---- P0: read A(half0) + B(nh0); stage B(t+1); MFMA q(0,0)
#pragma unroll
    for (int mi = 0; mi < 2; mi++)
#pragma unroll
      for (int kk = 0; kk < 2; kk++)
        af0[mi][kk] = *(const bf16x8*)(&la[cb][(wr*32 + mi*16 + c15)*64 + (((kk*4 + hi) ^ l7) * 8)]);
#pragma unroll
    for (int ni = 0; ni < 2; ni++)
#pragma unroll
      for (int kk = 0; kk < 2; kk++)
        bf0[ni][kk] = *(const bf16x8*)(&lb[cb][(wc*64 + ni*16 + c15)*64 + (((kk*4 + hi) ^ l7) * 8)]);
    if (t + 1 < NT) STB(nb, t + 1);
    __builtin_amdgcn_s_setprio(1);
#pragma unroll
    for (int mi = 0; mi < 2; mi++)
#pragma unroll
      for (int ni = 0; ni < 2; ni++)
#pragma unroll
        for (int kk = 0; kk < 2; kk++)
          acc[mi][ni] = mfma16(af0[mi][kk], bf0[ni][kk], acc[mi][ni]);
    __builtin_amdgcn_s_setprio(0);

    // ---- P1: read B(nh1); MFMA q(0,1)
#pragma unroll
    for (int ni = 0; ni < 2; ni++)
#pragma unroll
      for (int kk = 0; kk < 2; kk++)
        bf1[ni][kk] = *(const bf16x8*)(&lb[cb][(wc*64 + 32 + ni*16 + c15)*64 + (((kk*4 + hi) ^ l7) * 8)]);
    __builtin_amdgcn_s_setprio(1);
#pragma unroll
    for (int mi = 0; mi < 2; mi++)
#pragma unroll
      for (int ni = 0; ni < 2; ni++)
#pragma unroll
        for (int kk = 0; kk < 2; kk++)
          acc[mi][2 + ni] = mfma16(af0[mi][kk], bf1[ni][kk], acc[mi][2 + ni]);
    __builtin_amdgcn_s_setprio(0);

    // ---- P2: read A(half1); MFMA q(1,1)
#pragma unroll
    for (int mi = 0; mi < 2; mi++)
#pragma unroll
      for (int kk = 0; kk < 2; kk++)
        af1[mi][kk] = *(const bf16x8*)(&la[cb][(128 + wr*32 + mi*16 + c15)*64 + (((kk*4 + hi) ^ l7) * 8)]);
    __builtin_amdgcn_s_setprio(1);
#pragma unroll
    for (int mi = 0; mi < 2; mi++)
#pragma unroll
      for (int ni = 0; ni < 2; ni++)
#pragma unroll
        for (int kk = 0; kk < 2; kk++)
          acc[2 + mi][2 + ni] = mfma16(af1[mi][kk], bf1[ni][kk], acc[2 + mi][2 + ni]);
    __builtin_amdgcn_s_setprio(0);

    // ---- P3: MFMA q(1,0)
    __builtin_amdgcn_s_setprio(1);
#pragma unroll
    for (int mi = 0; mi < 2; mi++)
#pragma unroll
      for (int ni = 0; ni < 2; ni++)
#pragma unroll
        for (int kk = 0; kk < 2; kk++)
          acc[2 + mi][ni] = mfma16(af1[mi][kk], bf0[ni][kk], acc[2 + mi][ni]);
    __builtin_amdgcn_s_setprio(0);

    // ---- bottom: write A(t+1) (auto vmcnt waits areg; B(t+1) x2 newer fly),
    //      issue A(t+2), ensure B(t+1) landed, publish la/lb[nb]
    if (t + 1 < NT) {
      CVTWR(nb);
      if (t + 2 < NT) {
        LDA(t + 2);                                      // +8 (newest)
        asm volatile("s_waitcnt vmcnt(8)" ::: "memory"); // B(t+1) landed
      } else {
        asm volatile("s_waitcnt vmcnt(0)" ::: "memory"); // drain (B only)
      }
      asm volatile("s_waitcnt lgkmcnt(0)" ::: "memory"); // ds_writes drained
      __builtin_amdgcn_s_barrier();
      asm volatile("" ::: "memory");
    }
  }
#undef LDA
#undef CVTWR
#undef STB

  // ---- epilogue: bias + scatter (Q scaled; V transposed)
#pragma unroll
  for (int mi = 0; mi < 4; mi++) {
    int rbase = m0 + ((mi < 2) ? (wr*32 + mi*16) : (128 + wr*32 + (mi - 2)*16)) + hi*4;
#pragma unroll
    for (int ni = 0; ni < 4; ni++) {
      int n  = n0 + wc*64 + ni*16 + c15;
      int cz = n & 1023;
      float bvv = bias[cz];
      int h = cz >> 6, d = cz & 63;
      int b = rbase >> 11, s = rbase & 2047;
      if (z < 2) {
        bf16* C = z ? Kb : Qb;
        float sc = z ? 1.0f : QSCALE;
#pragma unroll
        for (int r = 0; r < 4; r++)
          C[((b*NH + h)*SEQ + (s + r))*HD + d] = (bf16)((acc[mi][ni][r] + bvv) * sc);
      } else {
        bf16x4 o;
#pragma unroll
        for (int r = 0; r < 4; r++) o[r] = (bf16)(acc[mi][ni][r] + bvv);
        *(bf16x4*)(Vtb + ((size_t)(b*NH + h)*HD + d)*SEQ + s) = o;
      }
    }
  }
}

// Output GEMM (r12/r13-proven 4-phase skeleton): float C = ctx @ Wo^T + bo
__global__ __launch_bounds__(512, 2) void gemm_out256(
    const bf16* __restrict__ A, const bf16* __restrict__ W,
    const float* __restrict__ bias, float* __restrict__ C)
{
  __shared__ __align__(16) bf16 la[2][256*64];
  __shared__ __align__(16) bf16 lb[2][128*64];

  const int K = 1024;
  int tid = threadIdx.x, wid = tid >> 6, lane = tid & 63;
  int wr = wid >> 1, wc = wid & 1;
  int c15 = lane & 15, hi = lane >> 4, l7 = lane & 7;

  int orig = blockIdx.x;
  int xcd = orig & 7, j = orig >> 3;             // j in 0..31
  int by = xcd * 4 + (j & 3);
  int bx = j >> 2;                               // 0..7
  int m0 = by * 256, n0 = bx * 128;

  int r8 = lane >> 3;
  int cu = (lane & 7) ^ r8;

  const bf16* gA = A + (size_t)m0 * K;
  const bf16* gW = W + (size_t)n0 * K;

#define STA(buf, h, kt)                                                        \
  {                                                                            \
    _Pragma("unroll")                                                          \
    for (int op = 0; op < 2; op++) {                                           \
      int rowl = (h)*128 + wid*16 + op*8 + r8;                                 \
      gload16(&la[buf][((h)*128 + wid*16 + op*8)*64],                          \
              gA + (size_t)rowl*K + (kt)*64 + cu*8);                           \
    }                                                                          \
  }
#define STB(buf, kt)                                                           \
  {                                                                            \
    _Pragma("unroll")                                                          \
    for (int op = 0; op < 2; op++) {                                           \
      int rowl = wid*16 + op*8 + r8;                                           \
      gload16(&lb[buf][(wid*16 + op*8)*64],                                    \
              gW + (size_t)rowl*K + (kt)*64 + cu*8);                           \
    }                                                                          \
  }

  f32x4 acc[4][4] = {};
  const int NT = K / 64;

  STB(0, 0);
  STA(0, 0, 0);
  STA(0, 1, 0);

  for (int t = 0; t < NT; ++t) {
    int cb = t & 1, nb = cb ^ 1;
    asm volatile("s_waitcnt vmcnt(2)" ::: "memory");
    __builtin_amdgcn_s_barrier();
    asm volatile("" ::: "memory");

    bf16x8 af0[2][2], af1[2][2], bf0[2][2], bf1[2][2];

#pragma unroll
    for (int mi = 0; mi < 2; mi++)
#pragma unroll
      for (int kk = 0; kk < 2; kk++)
        af0[mi][kk] = *(const bf16x8*)(&la[cb][(wr*32 + mi*16 + c15)*64 + (((kk*4 + hi) ^ l7) * 8)]);
#pragma unroll
    for (int ni = 0; ni < 2; ni++)
#pragma unroll
      for (int kk = 0; kk < 2; kk++)
        bf0[ni][kk] = *(const bf16x8*)(&lb[cb][(wc*64 + ni*16 + c15)*64 + (((kk*4 + hi) ^ l7) * 8)]);
    if (t + 1 < NT) STB(nb, t + 1);
    __builtin_amdgcn_s_setprio(1);
#pragma unroll
    for (int mi = 0; mi < 2; mi++)
#pragma unroll
      for (int ni = 0; ni < 2; ni++)
#pragma unroll
        for (int kk = 0; kk < 2; kk++)
          acc[mi][ni] = mfma16(af0[mi][kk], bf0[ni][kk], acc[mi][ni]);
    __builtin_amdgcn_s_setprio(0);

#pragma unroll
    for (int ni = 0; ni < 2; ni++)
#pragma unroll
      for (int kk = 0; kk < 2; kk++)
        bf1[ni][kk] = *(const bf16x8*)(&lb[cb][(wc*64 + 32 + ni*16 + c15)*64 + (((kk*4 + hi) ^ l7) * 8)]);
    if (t + 1 < NT) STA(nb, 0, t + 1);
    __builtin_amdgcn_s_setprio(1);
#pragma unroll
    for (int mi = 0; mi < 2; mi++)
#pragma unroll
      for (int ni = 0; ni < 2; ni++)
#pragma unroll
        for (int kk = 0; kk < 2; kk++)
          acc[mi][2 + ni] = mfma16(af0[mi][kk], bf1[ni][kk], acc[mi][2 + ni]);
    __builtin_amdgcn_s_setprio(0);

    if (t + 1 < NT) { asm volatile("s_waitcnt vmcnt(4)" ::: "memory"); }
    else            { asm volatile("s_waitcnt vmcnt(0)" ::: "memory"); }
    __builtin_amdgcn_s_barrier();
    asm volatile("" ::: "memory");

#pragma unroll
    for (int mi = 0; mi < 2; mi++)
#pragma unroll
      for (int kk = 0; kk < 2; kk++)
        af1[mi][kk] = *(const bf16x8*)(&la[cb][(128 + wr*32 + mi*16 + c15)*64 + (((kk*4 + hi) ^ l7) * 8)]);
    if (t + 1 < NT) STA(nb, 1, t + 1);
    __builtin_amdgcn_s_setprio(1);
#pragma unroll
    for (int mi = 0; mi < 2; mi++)
#pragma unroll
      for (int ni = 0; ni < 2; ni++)
#pragma unroll
        for (int kk = 0; kk < 2; kk++)
          acc[2 + mi][2 + ni] = mfma16(af1[mi][kk], bf1[ni][kk], acc[2 + mi][2 + ni]);
    __builtin_amdgcn_s_setprio(0);

    __builtin_amdgcn_s_setprio(1);
#pragma unroll
    for (int mi = 0; mi < 2; mi++)
#pragma unroll
      for (int ni = 0; ni < 2; ni++)
#pragma unroll
        for (int kk = 0; kk < 2; kk++)
          acc[2 + mi][ni] = mfma16(af1[mi][kk], bf0[ni][kk], acc[2 + mi][ni]);
    __builtin_amdgcn_s_setprio(0);
  }
#undef STA
#undef STB

#pragma unroll
  for (int mi = 0; mi < 4; mi++) {
    int rbase = m0 + ((mi < 2) ? (wr*32 + mi*16) : (128 + wr*32 + (mi - 2)*16)) + hi*4;
#pragma unroll
    for (int ni = 0; ni < 4; ni++) {
      int col = n0 + wc*64 + ni*16 + c15;
      float bvv = bias[col];
#pragma unroll
      for (int r = 0; r < 4; r++)
        C[(size_t)(rbase + r)*DM + col] = acc[mi][ni][r] + bvv;
    }
  }
}

// Flash attention v5 (best, verbatim): 2 q-tiles/wave, no-max exp2 softmax,
// MFMA row-sums, KVBLK=128 per barrier window, swizzled dbuf LDS.
__global__ __launch_bounds__(256, 2) void attn(
    const bf16* __restrict__ Q, const bf16* __restrict__ Kin,
    const bf16* __restrict__ Vt, bf16* __restrict__ ctx)
{
  __shared__ __align__(16) bf16 kt[2][128*64];  // [kv][d], 16B-unit swz: c8 ^= (kv&7)
  __shared__ __align__(16) bf16 vt[2][64*128];  // [d][kv], 16B-unit swz: c16 ^= (d&7)

  int tid = threadIdx.x, wid = tid >> 6, lane = tid & 63;
  int l31 = lane & 31, hi = lane >> 5, l7 = lane & 7;

  int orig = blockIdx.y * gridDim.x + blockIdx.x;
  int swz  = (orig & 7) * 64 + (orig >> 3);
  int bh   = swz >> 3, q0 = (swz & 7) * 256;

  const bf16* Qp = Q   + (size_t)bh*SEQ*HD;
  const bf16* Kp = Kin + (size_t)bh*SEQ*HD;
  const bf16* Vp = Vt  + (size_t)bh*HD*SEQ;
  int qw = q0 + wid*64;

  bf16x8 qf[2][4];
#pragma unroll
  for (int qt = 0; qt < 2; qt++)
#pragma unroll
    for (int dblk = 0; dblk < 4; dblk++)
      qf[qt][dblk] = *(const bf16x8*)(Qp + (size_t)(qw + qt*32 + l31)*HD + dblk*16 + hi*8);

  f32x16 po[2][2]  = {};
  f32x16 posum[2]  = {};

  bf16x8 onesv;
#pragma unroll
  for (int j = 0; j < 8; j++) onesv[j] = (bf16)1.0f;

  int r8 = lane >> 3;
  int ck = (lane & 7) ^ r8;
  int r16 = lane >> 4, c16v = lane & 15;

#define STAGE(buf, kv0)                                                        \
  {                                                                            \
    _Pragma("unroll")                                                          \
    for (int op = 0; op < 4; op++) {                                           \
      int rk = wid*32 + op*8 + r8;                                             \
      gload16(&kt[buf][(wid*32 + op*8)*64],                                    \
              Kp + (size_t)((kv0) + rk)*HD + ck*8);                            \
      int rv = wid*16 + op*4 + r16;                                            \
      gload16(&vt[buf][(wid*16 + op*4)*128],                                   \
              Vp + (size_t)rv*SEQ + (kv0) + ((c16v ^ (rv & 7))*8));            \
    }                                                                          \
  }

  STAGE(0, 0);
  __syncthreads();

  for (int it = 0; it < SEQ/128; ++it) {
    int cur = it & 1;
    if (it < SEQ/128 - 1) STAGE(cur ^ 1, (it + 1) * 128);

#pragma unroll
    for (int sub = 0; sub < 2; sub++) {
      f32x16 st[2][2] = {};
      __builtin_amdgcn_s_setprio(1);
#pragma unroll
      for (int kvt = 0; kvt < 2; kvt++) {
        int rowb = (sub*64 + kvt*32 + l31) * 64;
#pragma unroll
        for (int dblk = 0; dblk < 4; dblk++) {
          bf16x8 kf = *(const bf16x8*)(&kt[cur][rowb + (((dblk*2 + hi) ^ l7) * 8)]);
          st[0][kvt] = mfma32(kf, qf[0][dblk], st[0][kvt]);
          st[1][kvt] = mfma32(kf, qf[1][dblk], st[1][kvt]);
        }
      }
      __builtin_amdgcn_s_setprio(0);

      bf16x8 pa[2][2][2];
#pragma unroll
      for (int qt = 0; qt < 2; qt++) {
#pragma unroll
        for (int kvt = 0; kvt < 2; kvt++)
#pragma unroll
          for (int i = 0; i < 16; i++)
            st[qt][kvt][i] = exp2a(st[qt][kvt][i]);
#pragma unroll
        for (int kvt = 0; kvt < 2; kvt++)
#pragma unroll
          for (int cp = 0; cp < 2; cp++) {
            int m0 = 2*cp, m1 = 2*cp + 1;
            unsigned w0a = cvtpk(st[qt][kvt][4*m0+0], st[qt][kvt][4*m0+1]);
            unsigned w1a = cvtpk(st[qt][kvt][4*m0+2], st[qt][kvt][4*m0+3]);
            unsigned w0b = cvtpk(st[qt][kvt][4*m1+0], st[qt][kvt][4*m1+1]);
            unsigned w1b = cvtpk(st[qt][kvt][4*m1+2], st[qt][kvt][4*m1+3]);
            asm("v_permlane32_swap_b32 %0, %1" : "+v"(w0a), "+v"(w0b));
            asm("v_permlane32_swap_b32 %0, %1" : "+v"(w1a), "+v"(w1b));
            pa[qt][kvt][cp] = __builtin_bit_cast(bf16x8, (u32x4v){w0a, w1a, w0b, w1b});
          }
      }

      __builtin_amdgcn_s_setprio(1);
#pragma unroll
      for (int dt = 0; dt < 2; dt++) {
        int rowb = (dt*32 + l31) * 128;
#pragma unroll
        for (int c = 0; c < 4; c++) {
          bf16x8 vf = *(const bf16x8*)(&vt[cur][rowb + ((sub*8 + ((c*2 + hi) ^ l7)) * 8)]);
          po[0][dt] = mfma32(pa[0][c >> 1][c & 1], vf, po[0][dt]);
          po[1][dt] = mfma32(pa[1][c >> 1][c & 1], vf, po[1][dt]);
        }
      }
#pragma unroll
      for (int c = 0; c < 4; c++) {
        posum[0] = mfma32(pa[0][c >> 1][c & 1], onesv, posum[0]);
        posum[1] = mfma32(pa[1][c >> 1][c & 1], onesv, posum[1]);
      }
      __builtin_amdgcn_s_setprio(0);
    }

    __syncthreads();
  }
#undef STAGE

  int b = bh >> 4, h = bh & 15;
#pragma unroll
  for (int qt = 0; qt < 2; qt++)
#pragma unroll
    for (int reg = 0; reg < 16; reg++) {
      int qq = (reg & 3) + 8*(reg >> 2) + 4*hi;
      float inv = 1.0f / posum[qt][reg];
      int s = qw + qt*32 + qq;
      bf16* dst = ctx + (size_t)(b*SEQ + s)*DM + h*HD + l31;
      dst[0]  = (bf16)(po[qt][0][reg] * inv);
      dst[32] = (bf16)(po[qt][1][reg] * inv);
    }
}

extern "C" void kernel_launch(void* const* d_in, const int* in_sizes, int n_in,
                              void* d_out, int out_size, void* d_ws, size_t ws_size,
                              hipStream_t stream)
{
  const float* x  = (const float*)d_in[0];
  const float* Wq = (const float*)d_in[1];
  const float* bq = (const float*)d_in[2];
  const float* Wk = (const float*)d_in[3];
  const float* bk = (const float*)d_in[4];
  const float* Wv = (const float*)d_in[5];
  const float* bv = (const float*)d_in[6];
  const float* Wo = (const float*)d_in[7];
  const float* bo = (const float*)d_in[8];

  bf16* ws  = (bf16*)d_ws;
  bf16* ctx = ws;                          // [8192][1024] bf16 (attn output)
  bf16* Wb  = ws + ELEMS;                  // 4 x [1024][1024] bf16 weights (q,k,v,o)
  bf16* Qb  = ws + ELEMS + 4*WELEMS;       // [B,H,S,hd] (pre-scaled)
  bf16* Kb  = Qb + ELEMS;
  bf16* Vtb = Kb + ELEMS;                  // [B,H,hd,S]

  cvt_w<<<dim3(WELEMS/1024, 4), dim3(256), 0, stream>>>(Wq, Wk, Wv, Wo, Wb);
  gemm_qkv256<<<dim3(768), dim3(512), 0, stream>>>(
      x, Wb, bq, bk, bv, Qb, Kb, Vtb);
  attn<<<dim3(SEQ/256, BHN), dim3(256), 0, stream>>>(Qb, Kb, Vtb, ctx);
  gemm_out256<<<dim3(256), dim3(512), 0, stream>>>(
      ctx, Wb + 3*WELEMS, bo, (float*)d_out);
}